// Round 1
// baseline (322.190 us; speedup 1.0000x reference)
//
#include <hip/hip_runtime.h>
#include <hip/hip_bf16.h>
#include <stdint.h>

#define DIM 1024
#define ALPHA 7.18f
#define INV_N (1.0f/32768.0f)
#define NM1 32767.0f
#define LOG2E 1.44269504088896f
#define LN2 0.693147180559945f

typedef __attribute__((ext_vector_type(8))) short bfrag8;
typedef __attribute__((ext_vector_type(4))) float f32x4;

typedef const __attribute__((address_space(1))) void gv_t;
typedef __attribute__((address_space(3))) void lv_t;

__device__ __forceinline__ unsigned f2bf_bits(float f) {
    unsigned u = __float_as_uint(f);
    return (u + 0x7fffu + ((u >> 16) & 1u)) >> 16;
}

// ---------------- K1: column-parallel pass over outputs -------------------
// mean_sums[m][d] += o ; total_sq += o^2 ; own[], counts[]
__global__ __launch_bounds__(1024)
void k1_colsum(const float* __restrict__ outputs, const int* __restrict__ indices,
               const int* __restrict__ assignment, float* __restrict__ mean_sums,
               unsigned* __restrict__ counts, float* __restrict__ scalars,
               int* __restrict__ own_g) {
    __shared__ int sown[64];
    __shared__ float swsum[16];
    const int d = threadIdx.x;
    const int row0 = blockIdx.x * 64;
    if (d < 64) {
        int m = assignment[indices[row0 + d]];
        sown[d] = m;
        own_g[row0 + d] = m;
        atomicAdd(&counts[m], 1u);
    }
    __syncthreads();
    const float* p = outputs + (size_t)row0 * DIM + d;
    float msum = 0.f, ssum = 0.f;
    int curm = sown[0];
    #pragma unroll 8
    for (int r = 0; r < 64; ++r) {
        float o = p[(size_t)r * DIM];
        ssum = fmaf(o, o, ssum);
        int m = sown[r];
        if (m != curm) {  // uniform branch; never taken for run-structured data
            atomicAdd(&mean_sums[(size_t)curm * DIM + d], msum);
            msum = 0.f; curm = m;
        }
        msum += o;
    }
    atomicAdd(&mean_sums[(size_t)curm * DIM + d], msum);
    #pragma unroll
    for (int mk = 32; mk; mk >>= 1) ssum += __shfl_xor(ssum, mk, 64);
    if ((d & 63) == 0) swsum[d >> 6] = ssum;
    __syncthreads();
    if (d == 0) {
        float s = 0.f;
        #pragma unroll
        for (int w = 0; w < 16; ++w) s += swsum[w];
        atomicAdd(&scalars[0], s);
    }
}

// ---------------- K2: means -> bf16, ||mu||^2, var term -------------------
__global__ __launch_bounds__(256)
void k2_means(const float* __restrict__ mean_sums, const unsigned* __restrict__ counts,
              unsigned short* __restrict__ means_bf, float* __restrict__ msq,
              float* __restrict__ scalars) {
    const int m = blockIdx.x, t = threadIdx.x;
    const float* row = mean_sums + (size_t)m * DIM;
    unsigned short* ob = means_bf + (size_t)m * DIM;
    float sq = 0.f;
    #pragma unroll
    for (int i = 0; i < 4; ++i) {
        int dcol = t + i * 256;
        float mu = row[dcol] * (1.0f / 64.0f);   // segment_sum / D
        ob[dcol] = (unsigned short)f2bf_bits(mu);
        sq = fmaf(mu, mu, sq);
    }
    #pragma unroll
    for (int mk = 32; mk; mk >>= 1) sq += __shfl_xor(sq, mk, 64);
    __shared__ float sw[4];
    if ((t & 63) == 0) sw[t >> 6] = sq;
    __syncthreads();
    if (t == 0) {
        float s = sw[0] + sw[1] + sw[2] + sw[3];
        msq[m] = s;
        // var_sum = total_sq + sum_m (c_m - 128) * ||mu_m||^2
        atomicAdd(&scalars[1], ((float)counts[m] - 128.0f) * s);
    }
}

// ---------------- K3: scalars + output init ------------------------------
__global__ __launch_bounds__(512)
void k3_finalize(float* __restrict__ scalars, const float* __restrict__ msq,
                 const unsigned* __restrict__ counts, const float* __restrict__ loss_vector,
                 const float* __restrict__ loss_count, float* __restrict__ msl,
                 float* __restrict__ out) {
    const int t = threadIdx.x;
    float var_sum = scalars[0] + scalars[1];
    float inv_std = -NM1 / (2.0f * var_sum);     // 1/stdev (negative)
    msl[t] = msq[t] * inv_std * LOG2E;
    out[1 + t] = loss_vector[t] * INV_N;
    out[513 + t] = loss_count[t] + (float)counts[t];
    if (t == 0) {
        out[0] = 0.0f;
        out[1025] = var_sum / NM1;
        scalars[2] = inv_std;
    }
}

// ---------------- K4: fused GEMM + softmax-denom + loss ------------------
// Block: 64 rows x 512 cols (full M), 512 threads = 8 waves (2x4),
// 16x16x32 bf16 MFMA, BK=32, double-buffered LDS.
__global__ __launch_bounds__(512)
void k4_gemm(const float* __restrict__ outputs, const unsigned short* __restrict__ means_bf,
             const float* __restrict__ msl, const float* __restrict__ scalars,
             const int* __restrict__ own_g, float* __restrict__ out) {
    __shared__ short lA[2][64 * 32];    // 4 KB each, XOR-swizzled 16B slots
    __shared__ short lB[2][512 * 32];   // 32 KB each, XOR-swizzled 16B slots
    __shared__ float red_sum[64][4];
    __shared__ float red_own[64][4];

    const int tid  = threadIdx.x;
    const int lane = tid & 63;
    const int wid  = tid >> 6;      // 0..7
    const int wm   = wid >> 2;      // 0..1
    const int wn   = wid & 3;       // 0..3
    const int brow = blockIdx.x * 64;

    // A staging: thread -> (row rA, 4-float chunk kq)
    const int rA = tid >> 3;
    const int kq = tid & 7;
    const float* gA = outputs + (size_t)(brow + rA) * DIM + kq * 4;
    const int aw_byte = rA * 64 + (((kq >> 1) ^ ((rA >> 1) & 3)) << 4) + ((kq & 1) << 3);

    // B staging (global_load_lds): lane -> (row-in-16-group, physical slot)
    const int mB = lane >> 2;
    const int pB = lane & 3;

    // fragment read bases (swizzled)
    const int arow = wm * 32 + (lane & 15);
    const int ar_byte = arow * 64 + (((lane >> 4) ^ ((arow >> 1) & 3)) << 4);
    const int bcol = wn * 128 + (lane & 15);
    const int br_byte = bcol * 64 + (((lane >> 4) ^ ((bcol >> 1) & 3)) << 4);

    f32x4 acc[2][8];
    #pragma unroll
    for (int i = 0; i < 2; ++i)
        #pragma unroll
        for (int j = 0; j < 8; ++j)
            acc[i][j] = (f32x4){0.f, 0.f, 0.f, 0.f};

    // ---- prologue: stage tile 0
    {
        #pragma unroll
        for (int i = 0; i < 4; ++i) {
            int m = (wid * 4 + i) * 16 + mB;
            int s = pB ^ ((m >> 1) & 3);
            const char* gsrc = (const char*)means_bf + (size_t)m * 2048 + s * 16;
            char* ldst = (char*)&lB[0][0] + (wid * 4 + i) * 1024;
            __builtin_amdgcn_global_load_lds((gv_t*)gsrc, (lv_t*)ldst, 16, 0, 0);
        }
        float4 areg = *(const float4*)gA;
        unsigned lo = f2bf_bits(areg.x) | (f2bf_bits(areg.y) << 16);
        unsigned hi = f2bf_bits(areg.z) | (f2bf_bits(areg.w) << 16);
        *(uint2*)((char*)&lA[0][0] + aw_byte) = make_uint2(lo, hi);
    }
    __syncthreads();

    int cur = 0;
    for (int t = 0; t < 32; ++t) {
        const bool has_next = (t + 1) < 32;
        float4 anext;
        if (has_next) {
            anext = *(const float4*)(gA + (t + 1) * 32);           // issue early
            #pragma unroll
            for (int i = 0; i < 4; ++i) {
                int m = (wid * 4 + i) * 16 + mB;
                int s = pB ^ ((m >> 1) & 3);
                const char* gsrc = (const char*)means_bf + (size_t)m * 2048
                                   + (size_t)(t + 1) * 64 + s * 16;
                char* ldst = (char*)&lB[cur ^ 1][0] + (wid * 4 + i) * 1024;
                __builtin_amdgcn_global_load_lds((gv_t*)gsrc, (lv_t*)ldst, 16, 0, 0);
            }
        }
        // compute current tile
        const char* pa = (const char*)&lA[cur][0] + ar_byte;
        const char* pb = (const char*)&lB[cur][0] + br_byte;
        bfrag8 a0 = *(const bfrag8*)(pa);
        bfrag8 a1 = *(const bfrag8*)(pa + 1024);
        #pragma unroll
        for (int fn = 0; fn < 8; ++fn) {
            bfrag8 bf = *(const bfrag8*)(pb + fn * 1024);
            acc[0][fn] = __builtin_amdgcn_mfma_f32_16x16x32_bf16(a0, bf, acc[0][fn], 0, 0, 0);
            acc[1][fn] = __builtin_amdgcn_mfma_f32_16x16x32_bf16(a1, bf, acc[1][fn], 0, 0, 0);
        }
        if (has_next) {                                            // write late
            unsigned lo = f2bf_bits(anext.x) | (f2bf_bits(anext.y) << 16);
            unsigned hi = f2bf_bits(anext.z) | (f2bf_bits(anext.w) << 16);
            *(uint2*)((char*)&lA[cur ^ 1][0] + aw_byte) = make_uint2(lo, hi);
        }
        __syncthreads();
        cur ^= 1;
    }

    // ---- epilogue: exps, row sums, own capture
    float mslv[8];
    #pragma unroll
    for (int fn = 0; fn < 8; ++fn) mslv[fn] = msl[bcol + fn * 16];
    const float inv_std = scalars[2];
    const float c2k = -2.0f * inv_std * LOG2E;
    int ownv[2][4];
    #pragma unroll
    for (int fm = 0; fm < 2; ++fm)
        #pragma unroll
        for (int rg = 0; rg < 4; ++rg)
            ownv[fm][rg] = own_g[brow + wm * 32 + fm * 16 + ((lane >> 4) << 2) + rg];

    #pragma unroll
    for (int fm = 0; fm < 2; ++fm) {
        #pragma unroll
        for (int rg = 0; rg < 4; ++rg) {
            float sum = 0.f, oa = -1e30f;
            int ownr = ownv[fm][rg];
            #pragma unroll
            for (int fn = 0; fn < 8; ++fn) {
                float dot = acc[fm][fn][rg];
                float arg = fmaf(c2k, dot, mslv[fn]);   // log2-domain exponent
                sum += exp2f(arg);
                bool isown = (bcol + fn * 16) == ownr;
                oa = isown ? arg : oa;
            }
            #pragma unroll
            for (int mk = 1; mk < 16; mk <<= 1) {
                sum += __shfl_xor(sum, mk, 64);
                oa = fmaxf(oa, __shfl_xor(oa, mk, 64));
            }
            if ((lane & 15) == 0) {
                int r_in = wm * 32 + fm * 16 + ((lane >> 4) << 2) + rg;
                red_sum[r_in][wn] = sum;
                red_own[r_in][wn] = oa;
            }
        }
    }
    __syncthreads();

    if (tid < 64) {   // wave 0 finishes the 64 rows
        float s = red_sum[tid][0] + red_sum[tid][1] + red_sum[tid][2] + red_sum[tid][3];
        float oa = fmaxf(fmaxf(red_own[tid][0], red_own[tid][1]),
                         fmaxf(red_own[tid][2], red_own[tid][3]));
        float denom = s - exp2f(oa);
        float per_loss = fmaxf(ALPHA + LN2 * (log2f(denom) - oa), 0.f);
        int ownr = own_g[brow + tid];
        float ls = per_loss;
        #pragma unroll
        for (int mk = 1; mk < 64; mk <<= 1) ls += __shfl_xor(ls, mk, 64);
        int own0 = __shfl(ownr, 0, 64);
        if (__all(ownr == own0)) {
            if (tid == 0) atomicAdd(&out[1 + own0], ls * INV_N);
        } else {
            atomicAdd(&out[1 + ownr], per_loss * INV_N);
        }
        if (tid == 0) atomicAdd(&out[0], ls * INV_N);
    }
}

extern "C" void kernel_launch(void* const* d_in, const int* in_sizes, int n_in,
                              void* d_out, int out_size, void* d_ws, size_t ws_size,
                              hipStream_t stream) {
    const float* outputs     = (const float*)d_in[0];
    const int*   indices     = (const int*)d_in[1];
    const int*   assignment  = (const int*)d_in[2];
    const float* loss_vector = (const float*)d_in[3];
    const float* loss_count  = (const float*)d_in[4];
    float* out = (float*)d_out;

    char* ws = (char*)d_ws;
    float*          mean_sums = (float*)ws;                             // 2 MB
    unsigned*       counts    = (unsigned*)(ws + 2097152);              // 2 KB
    float*          scalars   = (float*)(ws + 2097152 + 2048);          // total_sq, var_acc, inv_std
    const size_t    ZB        = 2097152 + 2048 + 256;                   // zero region
    unsigned short* means_bf  = (unsigned short*)(ws + 2101248);        // 1 MB
    float*          msq       = (float*)(ws + 2101248 + 1048576);       // 2 KB
    float*          msl       = (float*)(ws + 2101248 + 1048576 + 2048);// 2 KB
    int*            own_g     = (int*)(ws + 2101248 + 1048576 + 4096);  // 128 KB

    hipMemsetAsync(d_ws, 0, ZB, stream);
    hipLaunchKernelGGL(k1_colsum, dim3(512), dim3(1024), 0, stream,
                       outputs, indices, assignment, mean_sums, counts, scalars, own_g);
    hipLaunchKernelGGL(k2_means, dim3(512), dim3(256), 0, stream,
                       mean_sums, counts, means_bf, msq, scalars);
    hipLaunchKernelGGL(k3_finalize, dim3(1), dim3(512), 0, stream,
                       scalars, msq, counts, loss_vector, loss_count, msl, out);
    hipLaunchKernelGGL(k4_gemm, dim3(512), dim3(512), 0, stream,
                       outputs, means_bf, msl, scalars, own_g, out);
}

// Round 2
// 279.473 us; speedup vs baseline: 1.1528x; 1.1528x over previous
//
#include <hip/hip_runtime.h>
#include <hip/hip_bf16.h>
#include <stdint.h>

#define DIM 1024
#define ALPHA 7.18f
#define INV_N (1.0f/32768.0f)
#define NM1 32767.0f
#define LOG2E 1.44269504088896f
#define LN2 0.693147180559945f

typedef __attribute__((ext_vector_type(8))) short bfrag8;
typedef __attribute__((ext_vector_type(4))) float f32x4;

typedef const __attribute__((address_space(1))) void gv_t;
typedef __attribute__((address_space(3))) void lv_t;

__device__ __forceinline__ unsigned f2bf_bits(float f) {
    unsigned u = __float_as_uint(f);
    return (u + 0x7fffu + ((u >> 16) & 1u)) >> 16;
}

// ---------------- K1: column sums + sq-sum + bf16 K-tiled A' -------------
// Block = 64 rows (one segment for run-structured data). 512 threads:
// thread = (rh = tid>>8, c4 = tid&255); c4 covers cols [c4*4, c4*4+4).
// A' layout: blk*131072 + t*4096 + r*64 + (kc ^ ((r>>1)&3))*16 + half*8
template<int APRIME>
__global__ __launch_bounds__(512)
void k1_colsum(const float* __restrict__ outputs, const int* __restrict__ indices,
               const int* __restrict__ assignment, float* __restrict__ mean_sums,
               unsigned* __restrict__ counts, float* __restrict__ scalars,
               int* __restrict__ own_g, unsigned short* __restrict__ a_bf) {
    __shared__ int sown[64];
    __shared__ int suni;
    __shared__ float4 spart[256];
    __shared__ float ssq[8];
    const int tid = threadIdx.x;
    const int row0 = blockIdx.x * 64;
    if (tid == 0) suni = 1;
    if (tid < 64) {
        int m = assignment[indices[row0 + tid]];
        sown[tid] = m;
        own_g[row0 + tid] = m;
        atomicAdd(&counts[m], 1u);
    }
    __syncthreads();
    if (tid < 63 && sown[tid] != sown[tid + 1]) suni = 0;
    __syncthreads();

    const int c4 = tid & 255;
    const int rh = tid >> 8;
    const float* gp = outputs + (size_t)(row0 + rh * 32) * DIM + c4 * 4;
    const int tt = c4 >> 3, kc = (c4 >> 1) & 3, half = c4 & 1;
    char* abase = (char*)a_bf + (size_t)blockIdx.x * 131072 + tt * 4096 + half * 8;

    float4 s4 = {0.f, 0.f, 0.f, 0.f};
    float sq = 0.f;
    if (suni) {
        #pragma unroll 8
        for (int r = 0; r < 32; ++r) {
            float4 v = *(const float4*)(gp + (size_t)r * DIM);
            sq = fmaf(v.x, v.x, sq); sq = fmaf(v.y, v.y, sq);
            sq = fmaf(v.z, v.z, sq); sq = fmaf(v.w, v.w, sq);
            s4.x += v.x; s4.y += v.y; s4.z += v.z; s4.w += v.w;
            if (APRIME) {
                int rr = rh * 32 + r;
                unsigned lo = f2bf_bits(v.x) | (f2bf_bits(v.y) << 16);
                unsigned hi = f2bf_bits(v.z) | (f2bf_bits(v.w) << 16);
                *(uint2*)(abase + rr * 64 + ((kc ^ ((rr >> 1) & 3)) << 4)) = make_uint2(lo, hi);
            }
        }
        if (rh) spart[c4] = s4;
        __syncthreads();
        if (!rh) {
            float4 o = spart[c4];
            float* dst = mean_sums + (size_t)sown[0] * DIM + c4 * 4;
            atomicAdd(dst + 0, s4.x + o.x);
            atomicAdd(dst + 1, s4.y + o.y);
            atomicAdd(dst + 2, s4.z + o.z);
            atomicAdd(dst + 3, s4.w + o.w);
        }
    } else {
        int curm = sown[rh * 32];
        for (int r = 0; r < 32; ++r) {
            int rr = rh * 32 + r;
            float4 v = *(const float4*)(gp + (size_t)r * DIM);
            int m = sown[rr];
            if (m != curm) {
                float* dst = mean_sums + (size_t)curm * DIM + c4 * 4;
                atomicAdd(dst + 0, s4.x); atomicAdd(dst + 1, s4.y);
                atomicAdd(dst + 2, s4.z); atomicAdd(dst + 3, s4.w);
                s4 = (float4){0.f, 0.f, 0.f, 0.f};
                curm = m;
            }
            sq = fmaf(v.x, v.x, sq); sq = fmaf(v.y, v.y, sq);
            sq = fmaf(v.z, v.z, sq); sq = fmaf(v.w, v.w, sq);
            s4.x += v.x; s4.y += v.y; s4.z += v.z; s4.w += v.w;
            if (APRIME) {
                unsigned lo = f2bf_bits(v.x) | (f2bf_bits(v.y) << 16);
                unsigned hi = f2bf_bits(v.z) | (f2bf_bits(v.w) << 16);
                *(uint2*)(abase + rr * 64 + ((kc ^ ((rr >> 1) & 3)) << 4)) = make_uint2(lo, hi);
            }
        }
        float* dst = mean_sums + (size_t)curm * DIM + c4 * 4;
        atomicAdd(dst + 0, s4.x); atomicAdd(dst + 1, s4.y);
        atomicAdd(dst + 2, s4.z); atomicAdd(dst + 3, s4.w);
    }
    #pragma unroll
    for (int mk = 32; mk; mk >>= 1) sq += __shfl_xor(sq, mk, 64);
    if ((tid & 63) == 0) ssq[tid >> 6] = sq;
    __syncthreads();
    if (tid == 0) {
        float s = 0.f;
        #pragma unroll
        for (int w = 0; w < 8; ++w) s += ssq[w];
        atomicAdd(&scalars[0], s);
    }
}

// ---------------- K2: means -> bf16 K-tiled B', ||mu||^2, var term -------
// B' layout: tt*32768 + m*64 + (kc ^ ((m>>1)&3))*16 + half*8
__global__ __launch_bounds__(256)
void k2_means(const float* __restrict__ mean_sums, const unsigned* __restrict__ counts,
              unsigned short* __restrict__ b_kt, float* __restrict__ msq,
              float* __restrict__ scalars) {
    const int m = blockIdx.x, t = threadIdx.x;
    const float* row = mean_sums + (size_t)m * DIM;
    float4 v = *(const float4*)(row + t * 4);
    float4 mu = {v.x * (1.0f/64.0f), v.y * (1.0f/64.0f), v.z * (1.0f/64.0f), v.w * (1.0f/64.0f)};
    const int tt = t >> 3, kc = (t >> 1) & 3, half = t & 1;
    unsigned lo = f2bf_bits(mu.x) | (f2bf_bits(mu.y) << 16);
    unsigned hi = f2bf_bits(mu.z) | (f2bf_bits(mu.w) << 16);
    *(uint2*)((char*)b_kt + tt * 32768 + m * 64 + ((kc ^ ((m >> 1) & 3)) << 4) + half * 8)
        = make_uint2(lo, hi);
    float sq = fmaf(mu.x, mu.x, fmaf(mu.y, mu.y, fmaf(mu.z, mu.z, mu.w * mu.w)));
    #pragma unroll
    for (int mk = 32; mk; mk >>= 1) sq += __shfl_xor(sq, mk, 64);
    __shared__ float sw[4];
    if ((t & 63) == 0) sw[t >> 6] = sq;
    __syncthreads();
    if (t == 0) {
        float s = sw[0] + sw[1] + sw[2] + sw[3];
        msq[m] = s;
        atomicAdd(&scalars[1], ((float)counts[m] - 128.0f) * s);
    }
}

// ---------------- K3: scalars + output init ------------------------------
__global__ __launch_bounds__(512)
void k3_finalize(float* __restrict__ scalars, const float* __restrict__ msq,
                 const unsigned* __restrict__ counts, const float* __restrict__ loss_vector,
                 const float* __restrict__ loss_count, float* __restrict__ msl,
                 float* __restrict__ out) {
    const int t = threadIdx.x;
    float var_sum = scalars[0] + scalars[1];
    float inv_std = -NM1 / (2.0f * var_sum);
    msl[t] = msq[t] * inv_std * LOG2E;
    out[1 + t] = loss_vector[t] * INV_N;
    out[513 + t] = loss_count[t] + (float)counts[t];
    if (t == 0) {
        out[0] = 0.0f;
        out[1025] = var_sum / NM1;
        scalars[2] = inv_std;
    }
}

// ---------------- K4: fused GEMM + softmax-denom + loss ------------------
// 64 rows x 512 cols (full M), 512 threads = 8 waves (2x4), BK=32, dbuf.
// All staging sources are CONTIGUOUS (K-tiled pre-swizzled A'/B').
template<int APRIME>
__global__ __launch_bounds__(512)
void k4_gemm(const float* __restrict__ outputs, const unsigned short* __restrict__ a_bf,
             const unsigned short* __restrict__ b_kt, const float* __restrict__ msl,
             const float* __restrict__ scalars, const int* __restrict__ own_g,
             float* __restrict__ out) {
    __shared__ short lA[2][64 * 32];    // 4 KB each
    __shared__ short lB[2][512 * 32];   // 32 KB each
    __shared__ float red_sum[64][4];
    __shared__ float red_own[64][4];

    const int tid  = threadIdx.x;
    const int lane = tid & 63;
    const int wid  = tid >> 6;
    const int wm   = wid >> 2;
    const int wn   = wid & 3;
    const int brow = blockIdx.x * 64;

    // fallback (f32 source) A staging
    const int rA = tid >> 3;
    const int kq = tid & 7;
    const float* gA = outputs + (size_t)(brow + rA) * DIM + kq * 4;
    const int aw_byte = rA * 64 + (((kq >> 1) ^ ((rA >> 1) & 3)) << 4) + ((kq & 1) << 3);

    const int arow = wm * 32 + (lane & 15);
    const int ar_byte = arow * 64 + (((lane >> 4) ^ ((arow >> 1) & 3)) << 4);
    const int bcol = wn * 128 + (lane & 15);
    const int br_byte = bcol * 64 + (((lane >> 4) ^ ((bcol >> 1) & 3)) << 4);

    const char* aprime = (const char*)a_bf + (size_t)blockIdx.x * 131072;
    const char* bbase  = (const char*)b_kt;

    f32x4 acc[2][8];
    #pragma unroll
    for (int i = 0; i < 2; ++i)
        #pragma unroll
        for (int j = 0; j < 8; ++j)
            acc[i][j] = (f32x4){0.f, 0.f, 0.f, 0.f};

    // ---- prologue: stage tile 0
    #pragma unroll
    for (int i = 0; i < 4; ++i) {
        const char* gsrc = bbase + (wid * 4 + i) * 1024 + lane * 16;
        char* ldst = (char*)&lB[0][0] + (wid * 4 + i) * 1024;
        __builtin_amdgcn_global_load_lds((gv_t*)gsrc, (lv_t*)ldst, 16, 0, 0);
    }
    if (APRIME) {
        if (wid < 4) {
            const char* gsrc = aprime + wid * 1024 + lane * 16;
            char* ldst = (char*)&lA[0][0] + wid * 1024;
            __builtin_amdgcn_global_load_lds((gv_t*)gsrc, (lv_t*)ldst, 16, 0, 0);
        }
    } else {
        float4 areg = *(const float4*)gA;
        unsigned lo = f2bf_bits(areg.x) | (f2bf_bits(areg.y) << 16);
        unsigned hi = f2bf_bits(areg.z) | (f2bf_bits(areg.w) << 16);
        *(uint2*)((char*)&lA[0][0] + aw_byte) = make_uint2(lo, hi);
    }
    __syncthreads();

    int cur = 0;
    for (int t = 0; t < 32; ++t) {
        const bool has_next = (t + 1) < 32;
        if (has_next) {
            #pragma unroll
            for (int i = 0; i < 4; ++i) {
                const char* gsrc = bbase + (size_t)(t + 1) * 32768 + (wid * 4 + i) * 1024 + lane * 16;
                char* ldst = (char*)&lB[cur ^ 1][0] + (wid * 4 + i) * 1024;
                __builtin_amdgcn_global_load_lds((gv_t*)gsrc, (lv_t*)ldst, 16, 0, 0);
            }
        }
        float4 anext;
        if (APRIME) {
            if (has_next && wid < 4) {
                const char* gsrc = aprime + (size_t)(t + 1) * 4096 + wid * 1024 + lane * 16;
                char* ldst = (char*)&lA[cur ^ 1][0] + wid * 1024;
                __builtin_amdgcn_global_load_lds((gv_t*)gsrc, (lv_t*)ldst, 16, 0, 0);
            }
        } else if (has_next) {
            anext = *(const float4*)(gA + (t + 1) * 32);
        }

        const char* pa = (const char*)&lA[cur][0] + ar_byte;
        const char* pb = (const char*)&lB[cur][0] + br_byte;
        bfrag8 a0 = *(const bfrag8*)(pa);
        bfrag8 a1 = *(const bfrag8*)(pa + 1024);
        #pragma unroll
        for (int fn = 0; fn < 8; ++fn) {
            bfrag8 bf = *(const bfrag8*)(pb + fn * 1024);
            acc[0][fn] = __builtin_amdgcn_mfma_f32_16x16x32_bf16(a0, bf, acc[0][fn], 0, 0, 0);
            acc[1][fn] = __builtin_amdgcn_mfma_f32_16x16x32_bf16(a1, bf, acc[1][fn], 0, 0, 0);
        }

        if (!APRIME && has_next) {
            unsigned lo = f2bf_bits(anext.x) | (f2bf_bits(anext.y) << 16);
            unsigned hi = f2bf_bits(anext.z) | (f2bf_bits(anext.w) << 16);
            *(uint2*)((char*)&lA[cur ^ 1][0] + aw_byte) = make_uint2(lo, hi);
        }
        __syncthreads();
        cur ^= 1;
    }

    // ---- epilogue
    float mslv[8];
    #pragma unroll
    for (int fn = 0; fn < 8; ++fn) mslv[fn] = msl[bcol + fn * 16];
    const float inv_std = scalars[2];
    const float c2k = -2.0f * inv_std * LOG2E;
    int ownv[2][4];
    #pragma unroll
    for (int fm = 0; fm < 2; ++fm)
        #pragma unroll
        for (int rg = 0; rg < 4; ++rg)
            ownv[fm][rg] = own_g[brow + wm * 32 + fm * 16 + ((lane >> 4) << 2) + rg];

    #pragma unroll
    for (int fm = 0; fm < 2; ++fm) {
        #pragma unroll
        for (int rg = 0; rg < 4; ++rg) {
            float sum = 0.f, oa = -1e30f;
            int ownr = ownv[fm][rg];
            #pragma unroll
            for (int fn = 0; fn < 8; ++fn) {
                float dot = acc[fm][fn][rg];
                float arg = fmaf(c2k, dot, mslv[fn]);
                sum += exp2f(arg);
                bool isown = (bcol + fn * 16) == ownr;
                oa = isown ? arg : oa;
            }
            #pragma unroll
            for (int mk = 1; mk < 16; mk <<= 1) {
                sum += __shfl_xor(sum, mk, 64);
                oa = fmaxf(oa, __shfl_xor(oa, mk, 64));
            }
            if ((lane & 15) == 0) {
                int r_in = wm * 32 + fm * 16 + ((lane >> 4) << 2) + rg;
                red_sum[r_in][wn] = sum;
                red_own[r_in][wn] = oa;
            }
        }
    }
    __syncthreads();

    if (tid < 64) {
        float s = red_sum[tid][0] + red_sum[tid][1] + red_sum[tid][2] + red_sum[tid][3];
        float oa = fmaxf(fmaxf(red_own[tid][0], red_own[tid][1]),
                         fmaxf(red_own[tid][2], red_own[tid][3]));
        float denom = s - exp2f(oa);
        float per_loss = fmaxf(ALPHA + LN2 * (log2f(denom) - oa), 0.f);
        int ownr = own_g[brow + tid];
        float ls = per_loss;
        #pragma unroll
        for (int mk = 1; mk < 64; mk <<= 1) ls += __shfl_xor(ls, mk, 64);
        int own0 = __shfl(ownr, 0, 64);
        if (__all(ownr == own0)) {
            if (tid == 0) atomicAdd(&out[1 + own0], ls * INV_N);
        } else {
            atomicAdd(&out[1 + ownr], per_loss * INV_N);
        }
        if (tid == 0) atomicAdd(&out[0], ls * INV_N);
    }
}

extern "C" void kernel_launch(void* const* d_in, const int* in_sizes, int n_in,
                              void* d_out, int out_size, void* d_ws, size_t ws_size,
                              hipStream_t stream) {
    const float* outputs     = (const float*)d_in[0];
    const int*   indices     = (const int*)d_in[1];
    const int*   assignment  = (const int*)d_in[2];
    const float* loss_vector = (const float*)d_in[3];
    const float* loss_count  = (const float*)d_in[4];
    float* out = (float*)d_out;

    char* ws = (char*)d_ws;
    float*          mean_sums = (float*)ws;                       // 2 MB
    unsigned*       counts    = (unsigned*)(ws + 2097152);        // 2 KB
    float*          scalars   = (float*)(ws + 2099200);           // 256 B
    const size_t    ZB        = 2099456;
    unsigned short* b_kt      = (unsigned short*)(ws + 2101248);  // 1 MB (K-tiled means)
    float*          msq       = (float*)(ws + 3149824);           // 2 KB
    float*          msl       = (float*)(ws + 3151872);           // 2 KB
    int*            own_g     = (int*)(ws + 3153920);             // 128 KB
    const size_t    A_OFF     = 4194304;
    unsigned short* a_bf      = (unsigned short*)(ws + A_OFF);    // 64 MB (K-tiled bf16 A)
    const size_t    NEED      = A_OFF + 67108864ULL;

    hipMemsetAsync(d_ws, 0, ZB, stream);
    if (ws_size >= NEED) {
        hipLaunchKernelGGL((k1_colsum<1>), dim3(512), dim3(512), 0, stream,
                           outputs, indices, assignment, mean_sums, counts, scalars, own_g, a_bf);
        hipLaunchKernelGGL(k2_means, dim3(512), dim3(256), 0, stream,
                           mean_sums, counts, b_kt, msq, scalars);
        hipLaunchKernelGGL(k3_finalize, dim3(1), dim3(512), 0, stream,
                           scalars, msq, counts, loss_vector, loss_count, msl, out);
        hipLaunchKernelGGL((k4_gemm<1>), dim3(512), dim3(512), 0, stream,
                           outputs, a_bf, b_kt, msl, scalars, own_g, out);
    } else {
        hipLaunchKernelGGL((k1_colsum<0>), dim3(512), dim3(512), 0, stream,
                           outputs, indices, assignment, mean_sums, counts, scalars, own_g, a_bf);
        hipLaunchKernelGGL(k2_means, dim3(512), dim3(256), 0, stream,
                           mean_sums, counts, b_kt, msq, scalars);
        hipLaunchKernelGGL(k3_finalize, dim3(1), dim3(512), 0, stream,
                           scalars, msq, counts, loss_vector, loss_count, msl, out);
        hipLaunchKernelGGL((k4_gemm<0>), dim3(512), dim3(512), 0, stream,
                           outputs, a_bf, b_kt, msl, scalars, own_g, out);
    }
}